// Round 14
// baseline (35434.433 us; speedup 1.0000x reference)
//
#include <hip/hip_runtime.h>
#include <math.h>

namespace {
constexpr int BATCH = 128;
constexpr int SEQ   = 512;
constexpr int NL    = 32;
constexpr int BOSTAG = 1;
constexpr int EOSTAG = 2;
}

#define AL(p)    __hip_atomic_load((p),       __ATOMIC_RELAXED, __HIP_MEMORY_SCOPE_AGENT)
#define AS(p, v) __hip_atomic_store((p), (v), __ATOMIC_RELAXED, __HIP_MEMORY_SCOPE_AGENT)
#define AADD(p)  __hip_atomic_fetch_add((p), 1u, __ATOMIC_RELAXED, __HIP_MEMORY_SCOPE_AGENT)

// coherent (cache-bypass) float4 load for cross-block data; element-wise
// relaxed agent atomics. R9-validated protocol (absmax 0, no fence).
__device__ __forceinline__ float4 aload4(const float* p) {
  float4 v;
  v.x = AL(p + 0); v.y = AL(p + 1); v.z = AL(p + 2); v.w = AL(p + 3);
  return v;
}

// tree-barrier counters; each padded to its own 128B line.
// 4 independent groups = (dir, batch-half); 8 sub-lines x 8 blocks per group.
__device__ unsigned g_sub[4][8][32];
__device__ unsigned g_root[4][32];

__global__ void reset_cnt_kernel() {
  const int i = threadIdx.x;           // 0..1023
  ((unsigned*)g_sub)[i] = 0u;          // 4*8*32 = 1024
  if (i < 4 * 32) ((unsigned*)g_root)[i] = 0u;
}

// Per-group tree barrier (64 blocks), NO cache fence. Cross-block data moves
// via agent write-through stores (drained by the vmcnt(0) the compiler emits
// before the first s_barrier) and agent bypass loads on the reader side
// (aload4). Read-only data (emb/x/Wout) stays plain-cached and now survives
// in L2 across steps. Control: sub-line fetch_add (8 serialized per line, 8
// lines parallel), 8th arrival promotes to root; waiters poll root with reads.
__device__ __forceinline__ void gbar(int g, int sub, unsigned epoch) {
  __syncthreads();
  if (threadIdx.x == 0) {
    const unsigned old = AADD(&g_sub[g][sub][0]);
    if (old == 8u * epoch - 1u)
      AADD(&g_root[g][0]);
    while (AL(&g_root[g][0]) < 8u * epoch)
      __builtin_amdgcn_s_sleep(2);
  }
  __syncthreads();
}

// hbuf layout: [2 parity][2 dir][128 b][512 u]  (65536 floats per (par,dir))
__global__ __launch_bounds__(512, 1)
void bilstm_coop(const int* __restrict__ x,
                 const float* __restrict__ emb,
                 const float* __restrict__ Wih_f, const float* __restrict__ Whh_f, const float* __restrict__ bf,
                 const float* __restrict__ Wih_b, const float* __restrict__ Whh_b, const float* __restrict__ bbias,
                 const float* __restrict__ Wout, const float* __restrict__ bout,
                 float* __restrict__ hbuf, float* __restrict__ em)
{
  __shared__ float4 WT4[8192];     // [k(1024)][slot(8)] gates i,f,g,o in .xyzw; slot = uu ^ ((k>>2)&7). 128 KB
  __shared__ float  em_red[512];   // [kc(16)][l(32)]
  float* WTf = (float*)WT4;

  const int tid = threadIdx.x, bi = blockIdx.x;
  // XCD-aligned group decode: group g = (dir,bh) occupies XCD residues {2g,2g+1}
  const int rX = bi & 7, qX = bi >> 3;
  const int grp = rX >> 1;                     // 0..3
  const int dir = grp >> 1, bh = grp & 1;
  const int ug  = (qX << 1) | (rX & 1);        // 0..63 unit slice
  const int u0  = ug * 8, b_base = bh * 64;
  const int bb  = b_base + ug;                 // emission batch owned by this block
  const int sub = ug >> 3;                     // barrier sub-line (8 blocks each)

  const float* Wih = dir ? Wih_b : Wih_f;
  const float* Whh = dir ? Whh_b : Whh_f;
  const float* bv  = dir ? bbias : bf;

  // ---- one-time: W slice -> LDS. WT4[k*8+slot] = gates of unit uu=slot^((k>>2)&7)
  for (int idx = tid; idx < 32768; idx += 512) {
    const int k = idx >> 5, r = idx & 31;
    const int gate = r & 3, uu = r >> 2;
    const int grow = gate * 512 + u0 + uu;
    const float v = (k < 512) ? Wih[(size_t)grow * 512 + k]
                              : Whh[(size_t)grow * 512 + (k - 512)];
    WTf[k * 32 + ((uu ^ ((k >> 2) & 7)) << 2) + gate] = v;
  }

  // compute roles: thread = (ks: k-split 8, ug2: unit-pair 4, bq: batch-quad 16)
  const int ks   = tid & 7;
  const int ug2  = (tid >> 3) & 3;
  const int bq   = ((tid >> 5) & 1) + 2 * (tid >> 6);   // 0..15
  const int bB   = b_base + 4 * bq;                      // first of 4 owned batches
  const int wb0 = 32 * ks + ((2 * ug2 + 0) ^ ks);
  const int wb1 = 32 * ks + ((2 * ug2 + 1) ^ ks);
  const int u_own = u0 + 2 * ug2 + (ks & 1);
  const int b_own = bB + (ks >> 1);
  // emission roles: l_ = label, kc = k-chunk of 32
  const int l_ = tid >> 4, kc = tid & 15;

  float bias_g[4];
  #pragma unroll
  for (int g = 0; g < 4; ++g) bias_g[g] = bv[g * 512 + u_own];
  float cstate = 0.f;

  // init parity-1 h (own bb row; group-local dependency)
  AS(&hbuf[131072 + dir * 65536 + (size_t)bb * 512 + tid], 0.f);
  unsigned epoch = 1;
  gbar(grp, sub, epoch); ++epoch;

  for (int s = 0; s < SEQ; ++s) {
    const int t = dir ? (SEQ - 1 - s) : s;

    // ---- pre-barrier: x gathers + first A chunk (plain cached, L2-warm)
    const float* e0 = emb + (size_t)x[(bB + 0) * SEQ + t] * 512 + 4 * ks;
    const float* e1 = emb + (size_t)x[(bB + 1) * SEQ + t] * 512 + 4 * ks;
    const float* e2 = emb + (size_t)x[(bB + 2) * SEQ + t] * 512 + 4 * ks;
    const float* e3 = emb + (size_t)x[(bB + 3) * SEQ + t] * 512 + 4 * ks;
    float4 cur[4], nxt[4];
    cur[0] = *(const float4*)e0; cur[1] = *(const float4*)e1;
    cur[2] = *(const float4*)e2; cur[3] = *(const float4*)e3;

    gbar(grp, sub, epoch); ++epoch;

    const float* hprev = hbuf + (size_t)((s + 1) & 1) * 131072 + dir * 65536;
    float*       hout  = hbuf + (size_t)((s    ) & 1) * 131072 + dir * 65536;

    // ---- emission for h_{s-1}: coherent burst load, consumed immediately ----
    if (s > 0) {
      const float* hb2 = hprev + (size_t)bb * 512 + kc * 32;
      float4 hq[8];
      #pragma unroll
      for (int q = 0; q < 8; ++q) hq[q] = aload4(hb2 + q * 4);
      const float* wr_ = Wout + (size_t)l_ * 1024 + dir * 512 + kc * 32;
      float emP = 0.f;
      #pragma unroll
      for (int q = 0; q < 8; ++q) {
        const float4 wv = *(const float4*)&wr_[q * 4];
        emP = fmaf(hq[q].x, wv.x, emP);
        emP = fmaf(hq[q].y, wv.y, emP);
        emP = fmaf(hq[q].z, wv.z, emP);
        emP = fmaf(hq[q].w, wv.w, emP);
      }
      em_red[kc * 32 + l_] = emP;
    }
    __syncthreads();
    if (s > 0 && tid < 32) {
      float p = 0.f;
      #pragma unroll
      for (int ksi = 0; ksi < 16; ++ksi) p += em_red[ksi * 32 + tid];
      const int te = dir ? (SEQ - s) : (s - 1);
      if (!dir) p += bout[tid];        // fwd contributes bout exactly once per te
      atomicAdd(em + ((size_t)bb * SEQ + te) * NL + tid, p);
    }

    const float* h0 = hprev + (size_t)(bB + 0) * 512 + 4 * ks;
    const float* h1 = hprev + (size_t)(bB + 1) * 512 + 4 * ks;
    const float* h2 = hprev + (size_t)(bB + 2) * 512 + 4 * ks;
    const float* h3 = hprev + (size_t)(bB + 3) * 512 + 4 * ks;

    // ---- gate GEMM: acc[unit n][batch r][gate], R=4 x U=2, S=8 k-split ----
    float acc0[4][4], acc1[4][4];
    #pragma unroll
    for (int r = 0; r < 4; ++r)
      #pragma unroll
      for (int g = 0; g < 4; ++g) { acc0[r][g] = 0.f; acc1[r][g] = 0.f; }

    // emb half: k = 4ks + 32i + j  (plain loads, L2-resident across steps)
    #pragma unroll 2
    for (int i = 0; i < 16; ++i) {
      if (i < 15) {
        nxt[0] = *(const float4*)(e0 + (i + 1) * 32);
        nxt[1] = *(const float4*)(e1 + (i + 1) * 32);
        nxt[2] = *(const float4*)(e2 + (i + 1) * 32);
        nxt[3] = *(const float4*)(e3 + (i + 1) * 32);
      } else {
        nxt[0] = aload4(h0); nxt[1] = aload4(h1);
        nxt[2] = aload4(h2); nxt[3] = aload4(h3);
      }
      #pragma unroll
      for (int j = 0; j < 4; ++j) {
        const float4 w0 = WT4[wb0 + 256 * i + 8 * j];
        const float4 w1 = WT4[wb1 + 256 * i + 8 * j];
        #pragma unroll
        for (int r = 0; r < 4; ++r) {
          const float a = (j == 0) ? cur[r].x : (j == 1) ? cur[r].y : (j == 2) ? cur[r].z : cur[r].w;
          acc0[r][0] = fmaf(w0.x, a, acc0[r][0]);
          acc0[r][1] = fmaf(w0.y, a, acc0[r][1]);
          acc0[r][2] = fmaf(w0.z, a, acc0[r][2]);
          acc0[r][3] = fmaf(w0.w, a, acc0[r][3]);
          acc1[r][0] = fmaf(w1.x, a, acc1[r][0]);
          acc1[r][1] = fmaf(w1.y, a, acc1[r][1]);
          acc1[r][2] = fmaf(w1.z, a, acc1[r][2]);
          acc1[r][3] = fmaf(w1.w, a, acc1[r][3]);
        }
      }
      #pragma unroll
      for (int r = 0; r < 4; ++r) cur[r] = nxt[r];
    }
    // h half: k = 512 + 4ks + 32i + j  (coherent loads, L3-direct)
    #pragma unroll 2
    for (int i = 0; i < 16; ++i) {
      if (i < 15) {
        nxt[0] = aload4(h0 + (i + 1) * 32);
        nxt[1] = aload4(h1 + (i + 1) * 32);
        nxt[2] = aload4(h2 + (i + 1) * 32);
        nxt[3] = aload4(h3 + (i + 1) * 32);
      }
      #pragma unroll
      for (int j = 0; j < 4; ++j) {
        const float4 w0 = WT4[4096 + wb0 + 256 * i + 8 * j];
        const float4 w1 = WT4[4096 + wb1 + 256 * i + 8 * j];
        #pragma unroll
        for (int r = 0; r < 4; ++r) {
          const float a = (j == 0) ? cur[r].x : (j == 1) ? cur[r].y : (j == 2) ? cur[r].z : cur[r].w;
          acc0[r][0] = fmaf(w0.x, a, acc0[r][0]);
          acc0[r][1] = fmaf(w0.y, a, acc0[r][1]);
          acc0[r][2] = fmaf(w0.z, a, acc0[r][2]);
          acc0[r][3] = fmaf(w0.w, a, acc0[r][3]);
          acc1[r][0] = fmaf(w1.x, a, acc1[r][0]);
          acc1[r][1] = fmaf(w1.y, a, acc1[r][1]);
          acc1[r][2] = fmaf(w1.z, a, acc1[r][2]);
          acc1[r][3] = fmaf(w1.w, a, acc1[r][3]);
        }
      }
      #pragma unroll
      for (int r = 0; r < 4; ++r) cur[r] = nxt[r];
    }

    // ---- butterfly over the 8 ks lanes (xor 1,2,4) ----
    #pragma unroll
    for (int m = 1; m < 8; m <<= 1)
      #pragma unroll
      for (int r = 0; r < 4; ++r)
        #pragma unroll
        for (int g = 0; g < 4; ++g) {
          acc0[r][g] += __shfl_xor(acc0[r][g], m, 64);
          acc1[r][g] += __shfl_xor(acc1[r][g], m, 64);
        }

    // lane ks owns (unit n'=ks&1, batch r'=ks>>1): static ternary select
    {
      float g4[4];
      #pragma unroll
      for (int g = 0; g < 4; ++g) {
        float v = acc0[0][g];
        v = (ks == 1) ? acc1[0][g] : v;
        v = (ks == 2) ? acc0[1][g] : v;
        v = (ks == 3) ? acc1[1][g] : v;
        v = (ks == 4) ? acc0[2][g] : v;
        v = (ks == 5) ? acc1[2][g] : v;
        v = (ks == 6) ? acc0[3][g] : v;
        v = (ks == 7) ? acc1[3][g] : v;
        g4[g] = v;
      }
      const float gi = g4[0] + bias_g[0];
      const float gf = g4[1] + bias_g[1];
      const float gg = g4[2] + bias_g[2];
      const float go = g4[3] + bias_g[3];
      const float si = 1.f / (1.f + expf(-gi));
      const float sf = 1.f / (1.f + expf(-gf));
      const float so = 1.f / (1.f + expf(-go));
      cstate = sf * cstate + si * tanhf(gg);
      AS(&hout[(size_t)b_own * 512 + u_own], so * tanhf(cstate));
    }
  }
  gbar(grp, sub, epoch); ++epoch;

  // ---- tail emission for the last h (parity 1) ----
  {
    const float* hb2 = hbuf + 131072 + dir * 65536 + (size_t)bb * 512 + kc * 32;
    const float* wr_ = Wout + (size_t)l_ * 1024 + dir * 512 + kc * 32;
    float emP = 0.f;
    #pragma unroll
    for (int q = 0; q < 8; ++q) {
      const float4 hv = aload4(hb2 + q * 4);
      const float4 wv = *(const float4*)&wr_[q * 4];
      emP = fmaf(hv.x, wv.x, emP);
      emP = fmaf(hv.y, wv.y, emP);
      emP = fmaf(hv.z, wv.z, emP);
      emP = fmaf(hv.w, wv.w, emP);
    }
    em_red[kc * 32 + l_] = emP;
    __syncthreads();
    if (tid < 32) {
      float p = 0.f;
      #pragma unroll
      for (int ksi = 0; ksi < 16; ++ksi) p += em_red[ksi * 32 + tid];
      const int te = dir ? 0 : (SEQ - 1);
      if (!dir) p += bout[tid];
      atomicAdd(em + ((size_t)bb * SEQ + te) * NL + tid, p);
    }
  }
}

__global__ __launch_bounds__(64)
void viterbi_kernel(const float* __restrict__ em, const int* __restrict__ mask,
                    const float* __restrict__ trans, float* __restrict__ out)
{
  __shared__ float tr[32][33];
  __shared__ float alpha[32];
  __shared__ float fin[32];
  __shared__ unsigned char bp[SEQ][32];
  __shared__ float path[SEQ];

  const int b = blockIdx.x, tid = threadIdx.x;
  for (int i = tid; i < 1024; i += 64) tr[i >> 5][i & 31] = trans[i];
  __syncthreads();

  const float* emB = em + (size_t)b * SEQ * NL;
  if (tid < 32) alpha[tid] = tr[BOSTAG][tid] + emB[tid];
  __syncthreads();

  for (int t = 1; t < SEQ; ++t) {
    float best = -INFINITY, e = 0.f;
    int arg = 0;
    if (tid < 32) {
      e = emB[t * NL + tid];
      #pragma unroll 4
      for (int p = 0; p < 32; ++p) {
        const float sc = (alpha[p] + tr[p][tid]) + e;  // np broadcast order
        if (sc > best) { best = sc; arg = p; }          // first-occurrence argmax
      }
    }
    __syncthreads();
    if (tid < 32) {
      const float m = (float)mask[b * SEQ + t];
      alpha[tid] = m * best + (1.f - m) * alpha[tid];
      bp[t][tid] = (unsigned char)arg;
    }
    __syncthreads();
  }

  if (tid < 32) fin[tid] = alpha[tid] + tr[tid][EOSTAG];
  __syncthreads();

  if (tid == 0) {
    float best = fin[0]; int tag = 0;
    for (int n = 1; n < 32; ++n) if (fin[n] > best) { best = fin[n]; tag = n; }
    out[b] = best;
    path[SEQ - 1] = (float)tag;
    for (int k = SEQ - 2; k >= 0; --k) {
      const int prev = bp[k + 1][tag];
      if (mask[b * SEQ + k + 1] > 0) tag = prev;
      path[k] = (float)tag;
    }
  }
  __syncthreads();
  for (int idx = tid; idx < SEQ; idx += 64)
    out[BATCH + (size_t)b * SEQ + idx] = path[idx];
}

extern "C" void kernel_launch(void* const* d_in, const int* in_sizes, int n_in,
                              void* d_out, int out_size, void* d_ws, size_t ws_size,
                              hipStream_t stream) {
  (void)in_sizes; (void)n_in; (void)out_size; (void)ws_size;
  const int*   x     = (const int*)d_in[0];
  const int*   mask  = (const int*)d_in[1];
  const float* emb   = (const float*)d_in[2];
  const float* Wih_f = (const float*)d_in[3];
  const float* Whh_f = (const float*)d_in[4];
  const float* bf    = (const float*)d_in[5];
  const float* Wih_b = (const float*)d_in[6];
  const float* Whh_b = (const float*)d_in[7];
  const float* bb    = (const float*)d_in[8];
  const float* Wout  = (const float*)d_in[9];
  const float* bout  = (const float*)d_in[10];
  const float* trans = (const float*)d_in[11];
  float* out  = (float*)d_out;
  float* hbuf = (float*)d_ws;                   // 262144 floats (1 MB)
  float* em   = hbuf + 262144;                  // 2097152 floats (8 MB)

  reset_cnt_kernel<<<dim3(1), dim3(1024), 0, stream>>>();
  hipMemsetAsync(em, 0, (size_t)2097152 * sizeof(float), stream);

  void* args[] = { (void*)&x, (void*)&emb,
                   (void*)&Wih_f, (void*)&Whh_f, (void*)&bf,
                   (void*)&Wih_b, (void*)&Whh_b, (void*)&bb,
                   (void*)&Wout, (void*)&bout,
                   (void*)&hbuf, (void*)&em };
  hipLaunchCooperativeKernel((void*)bilstm_coop, dim3(256), dim3(512), args, 0, stream);
  viterbi_kernel<<<dim3(128), dim3(64), 0, stream>>>(em, mask, trans, out);
}

// Round 17
// 29518.167 us; speedup vs baseline: 1.2004x; 1.2004x over previous
//
#include <hip/hip_runtime.h>
#include <math.h>

namespace {
constexpr int BATCH = 128;
constexpr int SEQ   = 512;
constexpr int NL    = 32;
constexpr int BOSTAG = 1;
constexpr int EOSTAG = 2;
}

#define AL(p)    __hip_atomic_load((p),       __ATOMIC_RELAXED, __HIP_MEMORY_SCOPE_AGENT)
#define AS(p, v) __hip_atomic_store((p), (v), __ATOMIC_RELAXED, __HIP_MEMORY_SCOPE_AGENT)
#define AADD(p)  __hip_atomic_fetch_add((p), 1u, __ATOMIC_RELAXED, __HIP_MEMORY_SCOPE_AGENT)

// tree-barrier counters; each padded to its own 128B line.
// 2 groups (batch-half), 128 blocks each: 16 sub-lines x 8 blocks.
__device__ unsigned g_sub[2][16][32];
__device__ unsigned g_root[2][32];

__global__ void reset_cnt_kernel() {
  const int i = threadIdx.x;             // 0..1023
  ((unsigned*)g_sub)[i] = 0u;            // 2*16*32 = 1024
  if (i < 64) ((unsigned*)g_root)[i] = 0u;
}

// Per-group tree barrier (128 blocks). Arrival: fetch_add on the sub line
// (8 serialized per line, 16 lines in parallel); the 8th arrival of the
// epoch promotes one add to the root line (16 serialized). Waiters poll
// root with plain reads. Cross-block stores are agent write-through
// (drained by the vmcnt(0) before the first s_barrier); acquire fence
// invalidates L1/L2 (r7/r8/r10/r12-proven semantics).
__device__ __forceinline__ void gbar(int g, int sub, unsigned epoch) {
  __syncthreads();
  if (threadIdx.x == 0) {
    const unsigned old = AADD(&g_sub[g][sub][0]);
    if (old == 8u * epoch - 1u)
      AADD(&g_root[g][0]);
    while (AL(&g_root[g][0]) < 16u * epoch)
      __builtin_amdgcn_s_sleep(2);
  }
  __builtin_amdgcn_fence(__ATOMIC_ACQUIRE, "agent");
  __syncthreads();
}

// hbuf layout: [2 parity][2 dir][128 b][512 u]  (65536 floats per (par,dir))
// 256 blocks x 1024 threads: 1 block/CU, 16 waves = 4 waves/SIMD.
// Thread-half dir = tid>>9 plays R16's "co-resident dir-block" role.
__global__ __launch_bounds__(1024, 4)
void bilstm_coop(const int* __restrict__ x,
                 const float* __restrict__ emb,
                 const float* __restrict__ Wih_f, const float* __restrict__ Whh_f, const float* __restrict__ bf,
                 const float* __restrict__ Wih_b, const float* __restrict__ Whh_b, const float* __restrict__ bbias,
                 const float* __restrict__ Wout, const float* __restrict__ bout,
                 float* __restrict__ hbuf, float* __restrict__ em)
{
  // Per-dir W slice: 4 units x 4 gates x 1024 k = 64 KB each.
  // WT4[dir][idx] = float4(gates i,f,g,o) of unit (u0+uu) at k, with
  // idx = (k>>3)*32 + ((k>>2)&1)*4 + (k&3)*8 + uu  -> wave reads hit all 32
  // banks (2 ks-parities x 4 uu quads), 4 addrs/bank = data floor.
  __shared__ float4 WT4[2][4096];
  __shared__ float  em_red[2][512];   // per dir: [kc(16)][l(32)]

  const int tid = threadIdx.x, bi = blockIdx.x;
  const int dir = tid >> 9;                    // thread-half = direction
  const int tl  = tid & 511;                   // local tid within dir-half
  const int bh  = bi & 1;
  const int ublock = bi >> 1;                  // 0..127: 4-unit slice
  const int u0  = ublock * 4, b_base = bh * 64;
  const int p   = ublock & 1;                  // k-half for emission split
  const int bb  = b_base + (ublock >> 1);      // emission batch owned (2 blocks/batch)
  const int sub = ublock >> 3;                 // 16 sub-lines x 8 blocks

  const float* Wih = dir ? Wih_b : Wih_f;
  const float* Whh = dir ? Whh_b : Whh_f;
  const float* bv  = dir ? bbias : bf;

  // ---- one-time: W slice -> LDS (permuted layout). 4096 float4 per dir. ----
  {
    float4* WTd = WT4[dir];
    for (int n = tl; n < 4096; n += 512) {
      const int k = n >> 2, uu = n & 3;
      const int idx = ((k >> 3) << 5) + (((k >> 2) & 1) << 2) + ((k & 3) << 3) + uu;
      float4 v;
      if (k < 512) {
        v.x = Wih[(size_t)(0 * 512 + u0 + uu) * 512 + k];
        v.y = Wih[(size_t)(1 * 512 + u0 + uu) * 512 + k];
        v.z = Wih[(size_t)(2 * 512 + u0 + uu) * 512 + k];
        v.w = Wih[(size_t)(3 * 512 + u0 + uu) * 512 + k];
      } else {
        const int kk = k - 512;
        v.x = Whh[(size_t)(0 * 512 + u0 + uu) * 512 + kk];
        v.y = Whh[(size_t)(1 * 512 + u0 + uu) * 512 + kk];
        v.z = Whh[(size_t)(2 * 512 + u0 + uu) * 512 + kk];
        v.w = Whh[(size_t)(3 * 512 + u0 + uu) * 512 + kk];
      }
      WTd[idx] = v;
    }
  }
  const float4* WTd = WT4[dir];

  // compute roles: thread = (ks: k-split 8, ug2: unit 0..3, bq: batch-quad 16)
  const int ks   = tl & 7;
  const int ug2  = (tl >> 3) & 3;
  const int bq   = tl >> 5;                    // 0..15
  const int bB   = b_base + 4 * bq;            // first of 4 owned batches
  // W float4 base for k = 4ks+32i+j: idx = wb + 128*i + 8*j
  const int wb   = ((ks >> 1) << 5) + ((ks & 1) << 2) + ug2;
  // emission roles
  const int l_ = tl >> 4, kc = tl & 15;        // label, k-chunk of 16 (within 256-half)

  float bias_g[4];
  #pragma unroll
  for (int g = 0; g < 4; ++g) bias_g[g] = bv[g * 512 + u0 + ug2];
  float cstate = 0.f;

  // init parity-1 h: each dir-half zeros its batch's k-half
  if (tl < 256)
    AS(&hbuf[131072 + dir * 65536 + (size_t)bb * 512 + p * 256 + tl], 0.f);
  unsigned epoch = 1;
  gbar(bh, sub, epoch); ++epoch;

  for (int s = 0; s < SEQ; ++s) {
    const int t = dir ? (SEQ - 1 - s) : s;

    // ---- pre-barrier: x gathers + first A chunk (latency hidden by spin) ----
    const float* e0 = emb + (size_t)x[(bB + 0) * SEQ + t] * 512 + 4 * ks;
    const float* e1 = emb + (size_t)x[(bB + 1) * SEQ + t] * 512 + 4 * ks;
    const float* e2 = emb + (size_t)x[(bB + 2) * SEQ + t] * 512 + 4 * ks;
    const float* e3 = emb + (size_t)x[(bB + 3) * SEQ + t] * 512 + 4 * ks;
    float4 cur[4], nxt[4];
    cur[0] = *(const float4*)e0; cur[1] = *(const float4*)e1;
    cur[2] = *(const float4*)e2; cur[3] = *(const float4*)e3;

    gbar(bh, sub, epoch); ++epoch;

    const float* hprev = hbuf + (size_t)((s + 1) & 1) * 131072 + dir * 65536;
    float*       hout  = hbuf + (size_t)((s    ) & 1) * 131072 + dir * 65536;

    // ---- emission for h_{s-1}: this block's k-half; hq dies immediately ----
    if (s > 0) {
      const float* hb2 = hprev + (size_t)bb * 512 + p * 256 + kc * 16;
      const float* wr_ = Wout + (size_t)l_ * 1024 + dir * 512 + p * 256 + kc * 16;
      float emP = 0.f;
      #pragma unroll
      for (int q = 0; q < 4; ++q) {
        const float4 hv = *(const float4*)(hb2 + q * 4);
        const float4 wv = *(const float4*)(wr_ + q * 4);
        emP = fmaf(hv.x, wv.x, emP);
        emP = fmaf(hv.y, wv.y, emP);
        emP = fmaf(hv.z, wv.z, emP);
        emP = fmaf(hv.w, wv.w, emP);
      }
      em_red[dir][kc * 32 + l_] = emP;
    }
    __syncthreads();
    if (s > 0 && tl < 32) {
      float pr = 0.f;
      #pragma unroll
      for (int ksi = 0; ksi < 16; ++ksi) pr += em_red[dir][ksi * 32 + tl];
      const int te = dir ? (SEQ - s) : (s - 1);
      if (!dir && p == 0) pr += bout[tl];    // bout exactly once per (b,te)
      atomicAdd(em + ((size_t)bb * SEQ + te) * NL + tl, pr);
    }

    const float* h0 = hprev + (size_t)(bB + 0) * 512 + 4 * ks;
    const float* h1 = hprev + (size_t)(bB + 1) * 512 + 4 * ks;
    const float* h2 = hprev + (size_t)(bB + 2) * 512 + 4 * ks;
    const float* h3 = hprev + (size_t)(bB + 3) * 512 + 4 * ks;

    // ---- gate GEMM: acc[batch r][gate], 1 unit/thread, S=8 k-split ----
    float acc[4][4];
    #pragma unroll
    for (int r = 0; r < 4; ++r)
      #pragma unroll
      for (int g = 0; g < 4; ++g) acc[r][g] = 0.f;

    // emb half: k = 4ks + 32i + j
    #pragma unroll 2
    for (int i = 0; i < 16; ++i) {
      if (i < 15) {
        nxt[0] = *(const float4*)(e0 + (i + 1) * 32);
        nxt[1] = *(const float4*)(e1 + (i + 1) * 32);
        nxt[2] = *(const float4*)(e2 + (i + 1) * 32);
        nxt[3] = *(const float4*)(e3 + (i + 1) * 32);
      } else {
        nxt[0] = *(const float4*)h0; nxt[1] = *(const float4*)h1;
        nxt[2] = *(const float4*)h2; nxt[3] = *(const float4*)h3;
      }
      #pragma unroll
      for (int j = 0; j < 4; ++j) {
        const float4 w0 = WTd[wb + 128 * i + 8 * j];
        #pragma unroll
        for (int r = 0; r < 4; ++r) {
          const float a = (j == 0) ? cur[r].x : (j == 1) ? cur[r].y
                        : (j == 2) ? cur[r].z : cur[r].w;
          acc[r][0] = fmaf(w0.x, a, acc[r][0]);
          acc[r][1] = fmaf(w0.y, a, acc[r][1]);
          acc[r][2] = fmaf(w0.z, a, acc[r][2]);
          acc[r][3] = fmaf(w0.w, a, acc[r][3]);
        }
      }
      #pragma unroll
      for (int r = 0; r < 4; ++r) cur[r] = nxt[r];
    }
    // h half: k = 512 + 4ks + 32i + j
    #pragma unroll 2
    for (int i = 0; i < 16; ++i) {
      if (i < 15) {
        nxt[0] = *(const float4*)(h0 + (i + 1) * 32);
        nxt[1] = *(const float4*)(h1 + (i + 1) * 32);
        nxt[2] = *(const float4*)(h2 + (i + 1) * 32);
        nxt[3] = *(const float4*)(h3 + (i + 1) * 32);
      }
      #pragma unroll
      for (int j = 0; j < 4; ++j) {
        const float4 w0 = WTd[2048 + wb + 128 * i + 8 * j];
        #pragma unroll
        for (int r = 0; r < 4; ++r) {
          const float a = (j == 0) ? cur[r].x : (j == 1) ? cur[r].y
                        : (j == 2) ? cur[r].z : cur[r].w;
          acc[r][0] = fmaf(w0.x, a, acc[r][0]);
          acc[r][1] = fmaf(w0.y, a, acc[r][1]);
          acc[r][2] = fmaf(w0.z, a, acc[r][2]);
          acc[r][3] = fmaf(w0.w, a, acc[r][3]);
        }
      }
      #pragma unroll
      for (int r = 0; r < 4; ++r) cur[r] = nxt[r];
    }

    // ---- butterfly over the 8 ks lanes (xor 1,2,4; intra-wave, intra-dir) ----
    #pragma unroll
    for (int m = 1; m < 8; m <<= 1)
      #pragma unroll
      for (int r = 0; r < 4; ++r)
        #pragma unroll
        for (int g = 0; g < 4; ++g)
          acc[r][g] += __shfl_xor(acc[r][g], m, 64);

    // lane ks (<4) owns batch bB+ks, unit u0+ug2: static ternary select
    {
      float g4[4];
      #pragma unroll
      for (int g = 0; g < 4; ++g) {
        float v = acc[0][g];
        v = (ks == 1) ? acc[1][g] : v;
        v = (ks == 2) ? acc[2][g] : v;
        v = (ks == 3) ? acc[3][g] : v;
        g4[g] = v;
      }
      const float gi = g4[0] + bias_g[0];
      const float gf = g4[1] + bias_g[1];
      const float gg = g4[2] + bias_g[2];
      const float go = g4[3] + bias_g[3];
      const float si = 1.f / (1.f + expf(-gi));
      const float sf = 1.f / (1.f + expf(-gf));
      const float so = 1.f / (1.f + expf(-go));
      cstate = sf * cstate + si * tanhf(gg);
      if (ks < 4)
        AS(&hout[(size_t)(bB + ks) * 512 + u0 + ug2], so * tanhf(cstate));
    }
  }
  gbar(bh, sub, epoch); ++epoch;

  // ---- tail emission for the last h (parity 1) ----
  {
    const float* hb2 = hbuf + 131072 + dir * 65536 + (size_t)bb * 512 + p * 256 + kc * 16;
    const float* wr_ = Wout + (size_t)l_ * 1024 + dir * 512 + p * 256 + kc * 16;
    float emP = 0.f;
    #pragma unroll
    for (int q = 0; q < 4; ++q) {
      const float4 hv = *(const float4*)(hb2 + q * 4);
      const float4 wv = *(const float4*)(wr_ + q * 4);
      emP = fmaf(hv.x, wv.x, emP);
      emP = fmaf(hv.y, wv.y, emP);
      emP = fmaf(hv.z, wv.z, emP);
      emP = fmaf(hv.w, wv.w, emP);
    }
    em_red[dir][kc * 32 + l_] = emP;
    __syncthreads();
    if (tl < 32) {
      float pr = 0.f;
      #pragma unroll
      for (int ksi = 0; ksi < 16; ++ksi) pr += em_red[dir][ksi * 32 + tl];
      const int te = dir ? 0 : (SEQ - 1);
      if (!dir && p == 0) pr += bout[tl];
      atomicAdd(em + ((size_t)bb * SEQ + te) * NL + tl, pr);
    }
  }
}

__global__ __launch_bounds__(64)
void viterbi_kernel(const float* __restrict__ em, const int* __restrict__ mask,
                    const float* __restrict__ trans, float* __restrict__ out)
{
  __shared__ float tr[32][33];
  __shared__ float alpha[32];
  __shared__ float fin[32];
  __shared__ unsigned char bp[SEQ][32];
  __shared__ float path[SEQ];

  const int b = blockIdx.x, tid = threadIdx.x;
  for (int i = tid; i < 1024; i += 64) tr[i >> 5][i & 31] = trans[i];
  __syncthreads();

  const float* emB = em + (size_t)b * SEQ * NL;
  if (tid < 32) alpha[tid] = tr[BOSTAG][tid] + emB[tid];
  __syncthreads();

  for (int t = 1; t < SEQ; ++t) {
    float best = -INFINITY, e = 0.f;
    int arg = 0;
    if (tid < 32) {
      e = emB[t * NL + tid];
      #pragma unroll 4
      for (int p = 0; p < 32; ++p) {
        const float sc = (alpha[p] + tr[p][tid]) + e;  // np broadcast order
        if (sc > best) { best = sc; arg = p; }          // first-occurrence argmax
      }
    }
    __syncthreads();
    if (tid < 32) {
      const float m = (float)mask[b * SEQ + t];
      alpha[tid] = m * best + (1.f - m) * alpha[tid];
      bp[t][tid] = (unsigned char)arg;
    }
    __syncthreads();
  }

  if (tid < 32) fin[tid] = alpha[tid] + tr[tid][EOSTAG];
  __syncthreads();

  if (tid == 0) {
    float best = fin[0]; int tag = 0;
    for (int n = 1; n < 32; ++n) if (fin[n] > best) { best = fin[n]; tag = n; }
    out[b] = best;
    path[SEQ - 1] = (float)tag;
    for (int k = SEQ - 2; k >= 0; --k) {
      const int prev = bp[k + 1][tag];
      if (mask[b * SEQ + k + 1] > 0) tag = prev;
      path[k] = (float)tag;
    }
  }
  __syncthreads();
  for (int idx = tid; idx < SEQ; idx += 64)
    out[BATCH + (size_t)b * SEQ + idx] = path[idx];
}

extern "C" void kernel_launch(void* const* d_in, const int* in_sizes, int n_in,
                              void* d_out, int out_size, void* d_ws, size_t ws_size,
                              hipStream_t stream) {
  (void)in_sizes; (void)n_in; (void)out_size; (void)ws_size;
  const int*   x     = (const int*)d_in[0];
  const int*   mask  = (const int*)d_in[1];
  const float* emb   = (const float*)d_in[2];
  const float* Wih_f = (const float*)d_in[3];
  const float* Whh_f = (const float*)d_in[4];
  const float* bf    = (const float*)d_in[5];
  const float* Wih_b = (const float*)d_in[6];
  const float* Whh_b = (const float*)d_in[7];
  const float* bb    = (const float*)d_in[8];
  const float* Wout  = (const float*)d_in[9];
  const float* bout  = (const float*)d_in[10];
  const float* trans = (const float*)d_in[11];
  float* out  = (float*)d_out;
  float* hbuf = (float*)d_ws;                   // 262144 floats (1 MB)
  float* em   = hbuf + 262144;                  // 2097152 floats (8 MB)

  reset_cnt_kernel<<<dim3(1), dim3(1024), 0, stream>>>();
  hipMemsetAsync(em, 0, (size_t)2097152 * sizeof(float), stream);

  void* args[] = { (void*)&x, (void*)&emb,
                   (void*)&Wih_f, (void*)&Whh_f, (void*)&bf,
                   (void*)&Wih_b, (void*)&Whh_b, (void*)&bb,
                   (void*)&Wout, (void*)&bout,
                   (void*)&hbuf, (void*)&em };
  hipLaunchCooperativeKernel((void*)bilstm_coop, dim3(256), dim3(1024), args, 0, stream);
  viterbi_kernel<<<dim3(128), dim3(64), 0, stream>>>(em, mask, trans, out);
}

// Round 18
// 20669.447 us; speedup vs baseline: 1.7143x; 1.4281x over previous
//
#include <hip/hip_runtime.h>
#include <math.h>

namespace {
constexpr int BATCH = 128;
constexpr int SEQ   = 512;
constexpr int NL    = 32;
constexpr int BOSTAG = 1;
constexpr int EOSTAG = 2;
}

#define AL(p)    __hip_atomic_load((p),       __ATOMIC_RELAXED, __HIP_MEMORY_SCOPE_AGENT)
#define AS(p, v) __hip_atomic_store((p), (v), __ATOMIC_RELAXED, __HIP_MEMORY_SCOPE_AGENT)
#define AADD(p)  __hip_atomic_fetch_add((p), 1u, __ATOMIC_RELAXED, __HIP_MEMORY_SCOPE_AGENT)

// tree-barrier counters; each padded to its own 128B line.
// 4 independent groups = (dir, batch-half); 8 sub-lines x 8 blocks per group.
__device__ unsigned g_sub[4][8][32];
__device__ unsigned g_root[4][32];

__global__ void reset_cnt_kernel() {
  const int i = threadIdx.x;           // 0..1023
  ((unsigned*)g_sub)[i] = 0u;          // 4*8*32 = 1024
  if (i < 4 * 32) ((unsigned*)g_root)[i] = 0u;
}

// Per-group tree barrier (64 blocks). Arrival: fetch_add on the sub line
// (8 serialized per line, 8 lines in parallel); the 8th arrival of the epoch
// promotes one add to the root line (8 serialized). Waiters poll root with
// plain reads. Cross-block stores are agent write-through (drained by the
// vmcnt(0) before the first s_barrier); acquire fence invalidates L1/L2
// (r7/r8/r10/r12-proven semantics).
__device__ __forceinline__ void gbar(int g, int sub, unsigned epoch) {
  __syncthreads();
  if (threadIdx.x == 0) {
    const unsigned old = AADD(&g_sub[g][sub][0]);
    if (old == 8u * epoch - 1u)
      AADD(&g_root[g][0]);
    while (AL(&g_root[g][0]) < 8u * epoch)
      __builtin_amdgcn_s_sleep(2);
  }
  __builtin_amdgcn_fence(__ATOMIC_ACQUIRE, "agent");
  __syncthreads();
}

// hbuf layout: [2 parity][2 dir][128 b][512 u]  (65536 floats per (par,dir))
__global__ __launch_bounds__(512, 1)
void bilstm_coop(const int* __restrict__ x,
                 const float* __restrict__ emb,
                 const float* __restrict__ Wih_f, const float* __restrict__ Whh_f, const float* __restrict__ bf,
                 const float* __restrict__ Wih_b, const float* __restrict__ Whh_b, const float* __restrict__ bbias,
                 const float* __restrict__ Wout, const float* __restrict__ bout,
                 float* __restrict__ hbuf, float* __restrict__ em)
{
  __shared__ float4 WT4[8192];     // [k(1024)][slot(8)] gates i,f,g,o in .xyzw; slot = uu ^ ((k>>2)&7). 128 KB
  float* WTf = (float*)WT4;

  const int tid = threadIdx.x, bi = blockIdx.x;
  // XCD-aligned group decode: group g = (dir,bh) occupies XCD residues {2g,2g+1}
  const int rX = bi & 7, qX = bi >> 3;
  const int grp = rX >> 1;                     // 0..3
  const int dir = grp >> 1, bh = grp & 1;
  const int ug  = (qX << 1) | (rX & 1);        // 0..63 unit slice
  const int u0  = ug * 8, b_base = bh * 64;
  const int bb  = b_base + ug;                 // emission batch owned by this block
  const int sub = ug >> 3;                     // barrier sub-line (8 blocks each)

  const float* Wih = dir ? Wih_b : Wih_f;
  const float* Whh = dir ? Whh_b : Whh_f;
  const float* bv  = dir ? bbias : bf;

  // ---- one-time: W slice -> LDS. WT4[k*8+slot] = gates of unit uu=slot^((k>>2)&7)
  for (int idx = tid; idx < 32768; idx += 512) {
    const int k = idx >> 5, r = idx & 31;
    const int gate = r & 3, uu = r >> 2;
    const int grow = gate * 512 + u0 + uu;
    const float v = (k < 512) ? Wih[(size_t)grow * 512 + k]
                              : Whh[(size_t)grow * 512 + (k - 512)];
    WTf[k * 32 + ((uu ^ ((k >> 2) & 7)) << 2) + gate] = v;
  }

  // compute roles: thread = (ks: k-split 8, ug2: unit-pair 4, bq: batch-quad 16)
  const int ks   = tid & 7;
  const int ug2  = (tid >> 3) & 3;
  const int bq   = ((tid >> 5) & 1) + 2 * (tid >> 6);   // 0..15
  const int bB   = b_base + 4 * bq;                      // first of 4 owned batches
  const int wb0 = 32 * ks + ((2 * ug2 + 0) ^ ks);
  const int wb1 = 32 * ks + ((2 * ug2 + 1) ^ ks);
  const int u_own = u0 + 2 * ug2 + (ks & 1);
  const int b_own = bB + (ks >> 1);
  // emission roles: l_ = label, kc = k-chunk of 32 (in-wave 16-lane group)
  const int l_ = tid >> 4, kc = tid & 15;

  float bias_g[4];
  #pragma unroll
  for (int g = 0; g < 4; ++g) bias_g[g] = bv[g * 512 + u_own];
  float cstate = 0.f;

  // init parity-1 h (own bb row; group-local dependency)
  AS(&hbuf[131072 + dir * 65536 + (size_t)bb * 512 + tid], 0.f);
  unsigned epoch = 1;
  gbar(grp, sub, epoch); ++epoch;

  for (int s = 0; s < SEQ; ++s) {
    const int t = dir ? (SEQ - 1 - s) : s;

    // ---- pre-barrier: x gathers + first A chunk (latency hidden by barrier)
    const float* e0 = emb + (size_t)x[(bB + 0) * SEQ + t] * 512 + 4 * ks;
    const float* e1 = emb + (size_t)x[(bB + 1) * SEQ + t] * 512 + 4 * ks;
    const float* e2 = emb + (size_t)x[(bB + 2) * SEQ + t] * 512 + 4 * ks;
    const float* e3 = emb + (size_t)x[(bB + 3) * SEQ + t] * 512 + 4 * ks;
    float4 cur[4], nxt[4];
    cur[0] = *(const float4*)e0; cur[1] = *(const float4*)e1;
    cur[2] = *(const float4*)e2; cur[3] = *(const float4*)e3;

    gbar(grp, sub, epoch); ++epoch;

    const float* hprev = hbuf + (size_t)((s + 1) & 1) * 131072 + dir * 65536;
    float*       hout  = hbuf + (size_t)((s    ) & 1) * 131072 + dir * 65536;

    // ---- emission for h_{s-1}: wave-local reduce (no LDS, no __syncthreads)
    if (s > 0) {
      const float* hb2 = hprev + (size_t)bb * 512 + kc * 32;
      const float* wr_ = Wout + (size_t)l_ * 1024 + dir * 512 + kc * 32;
      float emP = 0.f;
      #pragma unroll
      for (int q = 0; q < 8; ++q) {
        const float4 hv = *(const float4*)(hb2 + q * 4);
        const float4 wv = *(const float4*)(wr_ + q * 4);
        emP = fmaf(hv.x, wv.x, emP);
        emP = fmaf(hv.y, wv.y, emP);
        emP = fmaf(hv.z, wv.z, emP);
        emP = fmaf(hv.w, wv.w, emP);
      }
      // reduce over the 16 kc lanes (l_ constant within each 16-lane group)
      #pragma unroll
      for (int m = 1; m < 16; m <<= 1)
        emP += __shfl_xor(emP, m, 64);
      if (kc == 0) {
        const int te = dir ? (SEQ - s) : (s - 1);
        float pr = emP;
        if (!dir) pr += bout[l_];      // fwd contributes bout exactly once per te
        atomicAdd(em + ((size_t)bb * SEQ + te) * NL + l_, pr);
      }
    }

    const float* h0 = hprev + (size_t)(bB + 0) * 512 + 4 * ks;
    const float* h1 = hprev + (size_t)(bB + 1) * 512 + 4 * ks;
    const float* h2 = hprev + (size_t)(bB + 2) * 512 + 4 * ks;
    const float* h3 = hprev + (size_t)(bB + 3) * 512 + 4 * ks;

    // ---- gate GEMM: acc[unit n][batch r][gate], R=4 x U=2, S=8 k-split ----
    float acc0[4][4], acc1[4][4];
    #pragma unroll
    for (int r = 0; r < 4; ++r)
      #pragma unroll
      for (int g = 0; g < 4; ++g) { acc0[r][g] = 0.f; acc1[r][g] = 0.f; }

    // emb half: k = 4ks + 32i + j
    #pragma unroll 2
    for (int i = 0; i < 16; ++i) {
      if (i < 15) {
        nxt[0] = *(const float4*)(e0 + (i + 1) * 32);
        nxt[1] = *(const float4*)(e1 + (i + 1) * 32);
        nxt[2] = *(const float4*)(e2 + (i + 1) * 32);
        nxt[3] = *(const float4*)(e3 + (i + 1) * 32);
      } else {
        nxt[0] = *(const float4*)h0; nxt[1] = *(const float4*)h1;
        nxt[2] = *(const float4*)h2; nxt[3] = *(const float4*)h3;
      }
      #pragma unroll
      for (int j = 0; j < 4; ++j) {
        const float4 w0 = WT4[wb0 + 256 * i + 8 * j];
        const float4 w1 = WT4[wb1 + 256 * i + 8 * j];
        #pragma unroll
        for (int r = 0; r < 4; ++r) {
          const float a = (j == 0) ? cur[r].x : (j == 1) ? cur[r].y : (j == 2) ? cur[r].z : cur[r].w;
          acc0[r][0] = fmaf(w0.x, a, acc0[r][0]);
          acc0[r][1] = fmaf(w0.y, a, acc0[r][1]);
          acc0[r][2] = fmaf(w0.z, a, acc0[r][2]);
          acc0[r][3] = fmaf(w0.w, a, acc0[r][3]);
          acc1[r][0] = fmaf(w1.x, a, acc1[r][0]);
          acc1[r][1] = fmaf(w1.y, a, acc1[r][1]);
          acc1[r][2] = fmaf(w1.z, a, acc1[r][2]);
          acc1[r][3] = fmaf(w1.w, a, acc1[r][3]);
        }
      }
      #pragma unroll
      for (int r = 0; r < 4; ++r) cur[r] = nxt[r];
    }
    // h half: k = 512 + 4ks + 32i + j
    #pragma unroll 2
    for (int i = 0; i < 16; ++i) {
      if (i < 15) {
        nxt[0] = *(const float4*)(h0 + (i + 1) * 32);
        nxt[1] = *(const float4*)(h1 + (i + 1) * 32);
        nxt[2] = *(const float4*)(h2 + (i + 1) * 32);
        nxt[3] = *(const float4*)(h3 + (i + 1) * 32);
      }
      #pragma unroll
      for (int j = 0; j < 4; ++j) {
        const float4 w0 = WT4[4096 + wb0 + 256 * i + 8 * j];
        const float4 w1 = WT4[4096 + wb1 + 256 * i + 8 * j];
        #pragma unroll
        for (int r = 0; r < 4; ++r) {
          const float a = (j == 0) ? cur[r].x : (j == 1) ? cur[r].y : (j == 2) ? cur[r].z : cur[r].w;
          acc0[r][0] = fmaf(w0.x, a, acc0[r][0]);
          acc0[r][1] = fmaf(w0.y, a, acc0[r][1]);
          acc0[r][2] = fmaf(w0.z, a, acc0[r][2]);
          acc0[r][3] = fmaf(w0.w, a, acc0[r][3]);
          acc1[r][0] = fmaf(w1.x, a, acc1[r][0]);
          acc1[r][1] = fmaf(w1.y, a, acc1[r][1]);
          acc1[r][2] = fmaf(w1.z, a, acc1[r][2]);
          acc1[r][3] = fmaf(w1.w, a, acc1[r][3]);
        }
      }
      #pragma unroll
      for (int r = 0; r < 4; ++r) cur[r] = nxt[r];
    }

    // ---- butterfly over the 8 ks lanes (xor 1,2,4) ----
    #pragma unroll
    for (int m = 1; m < 8; m <<= 1)
      #pragma unroll
      for (int r = 0; r < 4; ++r)
        #pragma unroll
        for (int g = 0; g < 4; ++g) {
          acc0[r][g] += __shfl_xor(acc0[r][g], m, 64);
          acc1[r][g] += __shfl_xor(acc1[r][g], m, 64);
        }

    // lane ks owns (unit n'=ks&1, batch r'=ks>>1): static ternary select
    {
      float g4[4];
      #pragma unroll
      for (int g = 0; g < 4; ++g) {
        float v = acc0[0][g];
        v = (ks == 1) ? acc1[0][g] : v;
        v = (ks == 2) ? acc0[1][g] : v;
        v = (ks == 3) ? acc1[1][g] : v;
        v = (ks == 4) ? acc0[2][g] : v;
        v = (ks == 5) ? acc1[2][g] : v;
        v = (ks == 6) ? acc0[3][g] : v;
        v = (ks == 7) ? acc1[3][g] : v;
        g4[g] = v;
      }
      const float gi = g4[0] + bias_g[0];
      const float gf = g4[1] + bias_g[1];
      const float gg = g4[2] + bias_g[2];
      const float go = g4[3] + bias_g[3];
      const float si = 1.f / (1.f + expf(-gi));
      const float sf = 1.f / (1.f + expf(-gf));
      const float so = 1.f / (1.f + expf(-go));
      cstate = sf * cstate + si * tanhf(gg);
      AS(&hout[(size_t)b_own * 512 + u_own], so * tanhf(cstate));
    }
  }
  gbar(grp, sub, epoch); ++epoch;

  // ---- tail emission for the last h (parity 1), wave-local reduce ----
  {
    const float* hb2 = hbuf + 131072 + dir * 65536 + (size_t)bb * 512 + kc * 32;
    const float* wr_ = Wout + (size_t)l_ * 1024 + dir * 512 + kc * 32;
    float emP = 0.f;
    #pragma unroll
    for (int q = 0; q < 8; ++q) {
      const float4 hv = *(const float4*)(hb2 + q * 4);
      const float4 wv = *(const float4*)(wr_ + q * 4);
      emP = fmaf(hv.x, wv.x, emP);
      emP = fmaf(hv.y, wv.y, emP);
      emP = fmaf(hv.z, wv.z, emP);
      emP = fmaf(hv.w, wv.w, emP);
    }
    #pragma unroll
    for (int m = 1; m < 16; m <<= 1)
      emP += __shfl_xor(emP, m, 64);
    if (kc == 0) {
      const int te = dir ? 0 : (SEQ - 1);
      float pr = emP;
      if (!dir) pr += bout[l_];
      atomicAdd(em + ((size_t)bb * SEQ + te) * NL + l_, pr);
    }
  }
}

__global__ __launch_bounds__(64)
void viterbi_kernel(const float* __restrict__ em, const int* __restrict__ mask,
                    const float* __restrict__ trans, float* __restrict__ out)
{
  __shared__ float tr[32][33];
  __shared__ float alpha[32];
  __shared__ float fin[32];
  __shared__ unsigned char bp[SEQ][32];
  __shared__ float path[SEQ];

  const int b = blockIdx.x, tid = threadIdx.x;
  for (int i = tid; i < 1024; i += 64) tr[i >> 5][i & 31] = trans[i];
  __syncthreads();

  const float* emB = em + (size_t)b * SEQ * NL;
  if (tid < 32) alpha[tid] = tr[BOSTAG][tid] + emB[tid];
  __syncthreads();

  for (int t = 1; t < SEQ; ++t) {
    float best = -INFINITY, e = 0.f;
    int arg = 0;
    if (tid < 32) {
      e = emB[t * NL + tid];
      #pragma unroll 4
      for (int p = 0; p < 32; ++p) {
        const float sc = (alpha[p] + tr[p][tid]) + e;  // np broadcast order
        if (sc > best) { best = sc; arg = p; }          // first-occurrence argmax
      }
    }
    __syncthreads();
    if (tid < 32) {
      const float m = (float)mask[b * SEQ + t];
      alpha[tid] = m * best + (1.f - m) * alpha[tid];
      bp[t][tid] = (unsigned char)arg;
    }
    __syncthreads();
  }

  if (tid < 32) fin[tid] = alpha[tid] + tr[tid][EOSTAG];
  __syncthreads();

  if (tid == 0) {
    float best = fin[0]; int tag = 0;
    for (int n = 1; n < 32; ++n) if (fin[n] > best) { best = fin[n]; tag = n; }
    out[b] = best;
    path[SEQ - 1] = (float)tag;
    for (int k = SEQ - 2; k >= 0; --k) {
      const int prev = bp[k + 1][tag];
      if (mask[b * SEQ + k + 1] > 0) tag = prev;
      path[k] = (float)tag;
    }
  }
  __syncthreads();
  for (int idx = tid; idx < SEQ; idx += 64)
    out[BATCH + (size_t)b * SEQ + idx] = path[idx];
}

extern "C" void kernel_launch(void* const* d_in, const int* in_sizes, int n_in,
                              void* d_out, int out_size, void* d_ws, size_t ws_size,
                              hipStream_t stream) {
  (void)in_sizes; (void)n_in; (void)out_size; (void)ws_size;
  const int*   x     = (const int*)d_in[0];
  const int*   mask  = (const int*)d_in[1];
  const float* emb   = (const float*)d_in[2];
  const float* Wih_f = (const float*)d_in[3];
  const float* Whh_f = (const float*)d_in[4];
  const float* bf    = (const float*)d_in[5];
  const float* Wih_b = (const float*)d_in[6];
  const float* Whh_b = (const float*)d_in[7];
  const float* bb    = (const float*)d_in[8];
  const float* Wout  = (const float*)d_in[9];
  const float* bout  = (const float*)d_in[10];
  const float* trans = (const float*)d_in[11];
  float* out  = (float*)d_out;
  float* hbuf = (float*)d_ws;                   // 262144 floats (1 MB)
  float* em   = hbuf + 262144;                  // 2097152 floats (8 MB)

  reset_cnt_kernel<<<dim3(1), dim3(1024), 0, stream>>>();
  hipMemsetAsync(em, 0, (size_t)2097152 * sizeof(float), stream);

  void* args[] = { (void*)&x, (void*)&emb,
                   (void*)&Wih_f, (void*)&Whh_f, (void*)&bf,
                   (void*)&Wih_b, (void*)&Whh_b, (void*)&bb,
                   (void*)&Wout, (void*)&bout,
                   (void*)&hbuf, (void*)&em };
  hipLaunchCooperativeKernel((void*)bilstm_coop, dim3(256), dim3(512), args, 0, stream);
  viterbi_kernel<<<dim3(128), dim3(64), 0, stream>>>(em, mask, trans, out);
}

// Round 19
// 18127.278 us; speedup vs baseline: 1.9548x; 1.1402x over previous
//
#include <hip/hip_runtime.h>
#include <math.h>

namespace {
constexpr int BATCH = 128;
constexpr int SEQ   = 512;
constexpr int NL    = 32;
constexpr int BOSTAG = 1;
constexpr int EOSTAG = 2;
}

#define AL(p)    __hip_atomic_load((p),       __ATOMIC_RELAXED, __HIP_MEMORY_SCOPE_AGENT)
#define AS(p, v) __hip_atomic_store((p), (v), __ATOMIC_RELAXED, __HIP_MEMORY_SCOPE_AGENT)
#define AADD(p)  __hip_atomic_fetch_add((p), 1u, __ATOMIC_RELAXED, __HIP_MEMORY_SCOPE_AGENT)

// tree-barrier counters; each padded to its own 128B line.
// 4 independent groups = (dir, batch-half); 8 sub-lines x 8 blocks per group.
__device__ unsigned g_sub[4][8][32];
__device__ unsigned g_root[4][32];

__global__ void reset_cnt_kernel() {
  const int i = threadIdx.x;           // 0..1023
  ((unsigned*)g_sub)[i] = 0u;          // 4*8*32 = 1024
  if (i < 4 * 32) ((unsigned*)g_root)[i] = 0u;
}

// Split arrive/wait tree barrier (per group of 64 blocks; 8 sub-lines x 8).
// arrive: __syncthreads (drains this block's write-through h stores via the
// vmcnt(0) the compiler emits before s_barrier), then one fetch_add on the
// sub line; the 8th arrival of the epoch promotes one add to the root line.
// wait: poll root with plain reads, then acquire fence (invalidates L1/L2)
// + __syncthreads. Semantics = r12's fused gbar, split so independent
// compute can run between arrive and wait.
__device__ __forceinline__ void gbar_arrive(int g, int sub, unsigned epoch) {
  __syncthreads();
  if (threadIdx.x == 0) {
    const unsigned old = AADD(&g_sub[g][sub][0]);
    if (old == 8u * epoch - 1u)
      AADD(&g_root[g][0]);
  }
}
__device__ __forceinline__ void gbar_wait(int g, unsigned epoch) {
  if (threadIdx.x == 0) {
    while (AL(&g_root[g][0]) < 8u * epoch)
      __builtin_amdgcn_s_sleep(2);
  }
  __builtin_amdgcn_fence(__ATOMIC_ACQUIRE, "agent");
  __syncthreads();
}

// hbuf layout: [2 parity][2 dir][128 b][512 u]  (65536 floats per (par,dir))
__global__ __launch_bounds__(512, 1)
void bilstm_coop(const int* __restrict__ x,
                 const float* __restrict__ emb,
                 const float* __restrict__ Wih_f, const float* __restrict__ Whh_f, const float* __restrict__ bf,
                 const float* __restrict__ Wih_b, const float* __restrict__ Whh_b, const float* __restrict__ bbias,
                 const float* __restrict__ Wout, const float* __restrict__ bout,
                 float* __restrict__ hbuf, float* __restrict__ em)
{
  __shared__ float4 WT4[8192];     // [k(1024)][slot(8)] gates i,f,g,o in .xyzw; slot = uu ^ ((k>>2)&7). 128 KB
  float* WTf = (float*)WT4;

  const int tid = threadIdx.x, bi = blockIdx.x;
  // XCD-aligned group decode: group g = (dir,bh) occupies XCD residues {2g,2g+1}
  const int rX = bi & 7, qX = bi >> 3;
  const int grp = rX >> 1;                     // 0..3
  const int dir = grp >> 1, bh = grp & 1;
  const int ug  = (qX << 1) | (rX & 1);        // 0..63 unit slice
  const int u0  = ug * 8, b_base = bh * 64;
  const int bb  = b_base + ug;                 // emission batch owned by this block
  const int sub = ug >> 3;                     // barrier sub-line (8 blocks each)

  const float* Wih = dir ? Wih_b : Wih_f;
  const float* Whh = dir ? Whh_b : Whh_f;
  const float* bv  = dir ? bbias : bf;

  // ---- one-time: W slice -> LDS. WT4[k*8+slot] = gates of unit uu=slot^((k>>2)&7)
  for (int idx = tid; idx < 32768; idx += 512) {
    const int k = idx >> 5, r = idx & 31;
    const int gate = r & 3, uu = r >> 2;
    const int grow = gate * 512 + u0 + uu;
    const float v = (k < 512) ? Wih[(size_t)grow * 512 + k]
                              : Whh[(size_t)grow * 512 + (k - 512)];
    WTf[k * 32 + ((uu ^ ((k >> 2) & 7)) << 2) + gate] = v;
  }

  // compute roles: thread = (ks: k-split 8, ug2: unit-pair 4, bq: batch-quad 16)
  const int ks   = tid & 7;
  const int ug2  = (tid >> 3) & 3;
  const int bq   = ((tid >> 5) & 1) + 2 * (tid >> 6);   // 0..15
  const int bB   = b_base + 4 * bq;                      // first of 4 owned batches
  const int wb0 = 32 * ks + ((2 * ug2 + 0) ^ ks);
  const int wb1 = 32 * ks + ((2 * ug2 + 1) ^ ks);
  const int u_own = u0 + 2 * ug2 + (ks & 1);
  const int b_own = bB + (ks >> 1);
  // emission roles: l_ = label, kc = k-chunk of 32 (in-wave 16-lane group)
  const int l_ = tid >> 4, kc = tid & 15;

  float bias_g[4];
  #pragma unroll
  for (int g = 0; g < 4; ++g) bias_g[g] = bv[g * 512 + u_own];
  float cstate = 0.f;

  // init parity-1 h (own bb row; group-local dependency)
  AS(&hbuf[131072 + dir * 65536 + (size_t)bb * 512 + tid], 0.f);
  unsigned epoch = 1;
  gbar_arrive(grp, sub, epoch);
  gbar_wait(grp, epoch); ++epoch;

  for (int s = 0; s < SEQ; ++s) {
    const int t = dir ? (SEQ - 1 - s) : s;

    // ---- pre-arrive: x gathers + first emb chunk ----
    const float* e0 = emb + (size_t)x[(bB + 0) * SEQ + t] * 512 + 4 * ks;
    const float* e1 = emb + (size_t)x[(bB + 1) * SEQ + t] * 512 + 4 * ks;
    const float* e2 = emb + (size_t)x[(bB + 2) * SEQ + t] * 512 + 4 * ks;
    const float* e3 = emb + (size_t)x[(bB + 3) * SEQ + t] * 512 + 4 * ks;
    float4 cur[4], nxt[4];
    cur[0] = *(const float4*)e0; cur[1] = *(const float4*)e1;
    cur[2] = *(const float4*)e2; cur[3] = *(const float4*)e3;

    // ---- arrive: signals this block's h_{s-1} stores are drained ----
    gbar_arrive(grp, sub, epoch);

    // ---- emb-half GEMM (independent of h_{s-1}; overlaps barrier spin) ----
    float acc0[4][4], acc1[4][4];
    #pragma unroll
    for (int r = 0; r < 4; ++r)
      #pragma unroll
      for (int g = 0; g < 4; ++g) { acc0[r][g] = 0.f; acc1[r][g] = 0.f; }

    #pragma unroll 2
    for (int i = 0; i < 16; ++i) {
      if (i < 15) {
        nxt[0] = *(const float4*)(e0 + (i + 1) * 32);
        nxt[1] = *(const float4*)(e1 + (i + 1) * 32);
        nxt[2] = *(const float4*)(e2 + (i + 1) * 32);
        nxt[3] = *(const float4*)(e3 + (i + 1) * 32);
      }
      #pragma unroll
      for (int j = 0; j < 4; ++j) {
        const float4 w0 = WT4[wb0 + 256 * i + 8 * j];
        const float4 w1 = WT4[wb1 + 256 * i + 8 * j];
        #pragma unroll
        for (int r = 0; r < 4; ++r) {
          const float a = (j == 0) ? cur[r].x : (j == 1) ? cur[r].y : (j == 2) ? cur[r].z : cur[r].w;
          acc0[r][0] = fmaf(w0.x, a, acc0[r][0]);
          acc0[r][1] = fmaf(w0.y, a, acc0[r][1]);
          acc0[r][2] = fmaf(w0.z, a, acc0[r][2]);
          acc0[r][3] = fmaf(w0.w, a, acc0[r][3]);
          acc1[r][0] = fmaf(w1.x, a, acc1[r][0]);
          acc1[r][1] = fmaf(w1.y, a, acc1[r][1]);
          acc1[r][2] = fmaf(w1.z, a, acc1[r][2]);
          acc1[r][3] = fmaf(w1.w, a, acc1[r][3]);
        }
      }
      #pragma unroll
      for (int r = 0; r < 4; ++r) cur[r] = nxt[r];
    }

    // ---- wait: h_{s-1} from all blocks now visible ----
    gbar_wait(grp, epoch); ++epoch;

    const float* hprev = hbuf + (size_t)((s + 1) & 1) * 131072 + dir * 65536;
    float*       hout  = hbuf + (size_t)((s    ) & 1) * 131072 + dir * 65536;

    // ---- emission for h_{s-1}: wave-local reduce (covers h cur-load latency)
    const float* h0 = hprev + (size_t)(bB + 0) * 512 + 4 * ks;
    const float* h1 = hprev + (size_t)(bB + 1) * 512 + 4 * ks;
    const float* h2 = hprev + (size_t)(bB + 2) * 512 + 4 * ks;
    const float* h3 = hprev + (size_t)(bB + 3) * 512 + 4 * ks;
    cur[0] = *(const float4*)h0; cur[1] = *(const float4*)h1;
    cur[2] = *(const float4*)h2; cur[3] = *(const float4*)h3;

    if (s > 0) {
      const float* hb2 = hprev + (size_t)bb * 512 + kc * 32;
      const float* wr_ = Wout + (size_t)l_ * 1024 + dir * 512 + kc * 32;
      float emP = 0.f;
      #pragma unroll
      for (int q = 0; q < 8; ++q) {
        const float4 hv = *(const float4*)(hb2 + q * 4);
        const float4 wv = *(const float4*)(wr_ + q * 4);
        emP = fmaf(hv.x, wv.x, emP);
        emP = fmaf(hv.y, wv.y, emP);
        emP = fmaf(hv.z, wv.z, emP);
        emP = fmaf(hv.w, wv.w, emP);
      }
      #pragma unroll
      for (int m = 1; m < 16; m <<= 1)
        emP += __shfl_xor(emP, m, 64);
      if (kc == 0) {
        const int te = dir ? (SEQ - s) : (s - 1);
        float pr = emP;
        if (!dir) pr += bout[l_];      // fwd contributes bout exactly once per te
        atomicAdd(em + ((size_t)bb * SEQ + te) * NL + l_, pr);
      }
    }

    // ---- h-half GEMM: k = 512 + 4ks + 32i + j ----
    #pragma unroll 2
    for (int i = 0; i < 16; ++i) {
      if (i < 15) {
        nxt[0] = *(const float4*)(h0 + (i + 1) * 32);
        nxt[1] = *(const float4*)(h1 + (i + 1) * 32);
        nxt[2] = *(const float4*)(h2 + (i + 1) * 32);
        nxt[3] = *(const float4*)(h3 + (i + 1) * 32);
      }
      #pragma unroll
      for (int j = 0; j < 4; ++j) {
        const float4 w0 = WT4[4096 + wb0 + 256 * i + 8 * j];
        const float4 w1 = WT4[4096 + wb1 + 256 * i + 8 * j];
        #pragma unroll
        for (int r = 0; r < 4; ++r) {
          const float a = (j == 0) ? cur[r].x : (j == 1) ? cur[r].y : (j == 2) ? cur[r].z : cur[r].w;
          acc0[r][0] = fmaf(w0.x, a, acc0[r][0]);
          acc0[r][1] = fmaf(w0.y, a, acc0[r][1]);
          acc0[r][2] = fmaf(w0.z, a, acc0[r][2]);
          acc0[r][3] = fmaf(w0.w, a, acc0[r][3]);
          acc1[r][0] = fmaf(w1.x, a, acc1[r][0]);
          acc1[r][1] = fmaf(w1.y, a, acc1[r][1]);
          acc1[r][2] = fmaf(w1.z, a, acc1[r][2]);
          acc1[r][3] = fmaf(w1.w, a, acc1[r][3]);
        }
      }
      #pragma unroll
      for (int r = 0; r < 4; ++r) cur[r] = nxt[r];
    }

    // ---- butterfly over the 8 ks lanes (xor 1,2,4) ----
    #pragma unroll
    for (int m = 1; m < 8; m <<= 1)
      #pragma unroll
      for (int r = 0; r < 4; ++r)
        #pragma unroll
        for (int g = 0; g < 4; ++g) {
          acc0[r][g] += __shfl_xor(acc0[r][g], m, 64);
          acc1[r][g] += __shfl_xor(acc1[r][g], m, 64);
        }

    // lane ks owns (unit n'=ks&1, batch r'=ks>>1): static ternary select
    {
      float g4[4];
      #pragma unroll
      for (int g = 0; g < 4; ++g) {
        float v = acc0[0][g];
        v = (ks == 1) ? acc1[0][g] : v;
        v = (ks == 2) ? acc0[1][g] : v;
        v = (ks == 3) ? acc1[1][g] : v;
        v = (ks == 4) ? acc0[2][g] : v;
        v = (ks == 5) ? acc1[2][g] : v;
        v = (ks == 6) ? acc0[3][g] : v;
        v = (ks == 7) ? acc1[3][g] : v;
        g4[g] = v;
      }
      const float gi = g4[0] + bias_g[0];
      const float gf = g4[1] + bias_g[1];
      const float gg = g4[2] + bias_g[2];
      const float go = g4[3] + bias_g[3];
      const float si = 1.f / (1.f + expf(-gi));
      const float sf = 1.f / (1.f + expf(-gf));
      const float so = 1.f / (1.f + expf(-go));
      cstate = sf * cstate + si * tanhf(gg);
      AS(&hout[(size_t)b_own * 512 + u_own], so * tanhf(cstate));
    }
  }
  gbar_arrive(grp, sub, epoch);
  gbar_wait(grp, epoch); ++epoch;

  // ---- tail emission for the last h (parity 1), wave-local reduce ----
  {
    const float* hb2 = hbuf + 131072 + dir * 65536 + (size_t)bb * 512 + kc * 32;
    const float* wr_ = Wout + (size_t)l_ * 1024 + dir * 512 + kc * 32;
    float emP = 0.f;
    #pragma unroll
    for (int q = 0; q < 8; ++q) {
      const float4 hv = *(const float4*)(hb2 + q * 4);
      const float4 wv = *(const float4*)(wr_ + q * 4);
      emP = fmaf(hv.x, wv.x, emP);
      emP = fmaf(hv.y, wv.y, emP);
      emP = fmaf(hv.z, wv.z, emP);
      emP = fmaf(hv.w, wv.w, emP);
    }
    #pragma unroll
    for (int m = 1; m < 16; m <<= 1)
      emP += __shfl_xor(emP, m, 64);
    if (kc == 0) {
      const int te = dir ? 0 : (SEQ - 1);
      float pr = emP;
      if (!dir) pr += bout[l_];
      atomicAdd(em + ((size_t)bb * SEQ + te) * NL + l_, pr);
    }
  }
}

__global__ __launch_bounds__(64)
void viterbi_kernel(const float* __restrict__ em, const int* __restrict__ mask,
                    const float* __restrict__ trans, float* __restrict__ out)
{
  __shared__ float tr[32][33];
  __shared__ float alpha[32];
  __shared__ float fin[32];
  __shared__ unsigned char bp[SEQ][32];
  __shared__ float path[SEQ];

  const int b = blockIdx.x, tid = threadIdx.x;
  for (int i = tid; i < 1024; i += 64) tr[i >> 5][i & 31] = trans[i];
  __syncthreads();

  const float* emB = em + (size_t)b * SEQ * NL;
  if (tid < 32) alpha[tid] = tr[BOSTAG][tid] + emB[tid];
  __syncthreads();

  for (int t = 1; t < SEQ; ++t) {
    float best = -INFINITY, e = 0.f;
    int arg = 0;
    if (tid < 32) {
      e = emB[t * NL + tid];
      #pragma unroll 4
      for (int p = 0; p < 32; ++p) {
        const float sc = (alpha[p] + tr[p][tid]) + e;  // np broadcast order
        if (sc > best) { best = sc; arg = p; }          // first-occurrence argmax
      }
    }
    __syncthreads();
    if (tid < 32) {
      const float m = (float)mask[b * SEQ + t];
      alpha[tid] = m * best + (1.f - m) * alpha[tid];
      bp[t][tid] = (unsigned char)arg;
    }
    __syncthreads();
  }

  if (tid < 32) fin[tid] = alpha[tid] + tr[tid][EOSTAG];
  __syncthreads();

  if (tid == 0) {
    float best = fin[0]; int tag = 0;
    for (int n = 1; n < 32; ++n) if (fin[n] > best) { best = fin[n]; tag = n; }
    out[b] = best;
    path[SEQ - 1] = (float)tag;
    for (int k = SEQ - 2; k >= 0; --k) {
      const int prev = bp[k + 1][tag];
      if (mask[b * SEQ + k + 1] > 0) tag = prev;
      path[k] = (float)tag;
    }
  }
  __syncthreads();
  for (int idx = tid; idx < SEQ; idx += 64)
    out[BATCH + (size_t)b * SEQ + idx] = path[idx];
}

extern "C" void kernel_launch(void* const* d_in, const int* in_sizes, int n_in,
                              void* d_out, int out_size, void* d_ws, size_t ws_size,
                              hipStream_t stream) {
  (void)in_sizes; (void)n_in; (void)out_size; (void)ws_size;
  const int*   x     = (const int*)d_in[0];
  const int*   mask  = (const int*)d_in[1];
  const float* emb   = (const float*)d_in[2];
  const float* Wih_f = (const float*)d_in[3];
  const float* Whh_f = (const float*)d_in[4];
  const float* bf    = (const float*)d_in[5];
  const float* Wih_b = (const float*)d_in[6];
  const float* Whh_b = (const float*)d_in[7];
  const float* bb    = (const float*)d_in[8];
  const float* Wout  = (const float*)d_in[9];
  const float* bout  = (const float*)d_in[10];
  const float* trans = (const float*)d_in[11];
  float* out  = (float*)d_out;
  float* hbuf = (float*)d_ws;                   // 262144 floats (1 MB)
  float* em   = hbuf + 262144;                  // 2097152 floats (8 MB)

  reset_cnt_kernel<<<dim3(1), dim3(1024), 0, stream>>>();
  hipMemsetAsync(em, 0, (size_t)2097152 * sizeof(float), stream);

  void* args[] = { (void*)&x, (void*)&emb,
                   (void*)&Wih_f, (void*)&Whh_f, (void*)&bf,
                   (void*)&Wih_b, (void*)&Whh_b, (void*)&bb,
                   (void*)&Wout, (void*)&bout,
                   (void*)&hbuf, (void*)&em };
  hipLaunchCooperativeKernel((void*)bilstm_coop, dim3(256), dim3(512), args, 0, stream);
  viterbi_kernel<<<dim3(128), dim3(64), 0, stream>>>(em, mask, trans, out);
}